// Round 12
// baseline (420.908 us; speedup 1.0000x reference)
//
#include <hip/hip_runtime.h>
#include <hip/hip_bf16.h>

// Problem constants (L,N,E,H,D) = (2048,4,512,8,64)
#define E_DIM 512
#define N_BATCH 4
#define L_SEQ 2048
#define N_HEADS 8
#define H_DIM 64
#define N_ROWS (L_SEQ * N_BATCH) /* 8192 */
#define EPS_F 1e-6f
#define SC_Q 0.18033688f  /* 0.125 * log2(e): scores come out in log2 space */

typedef __attribute__((ext_vector_type(8))) short bf16x8;
typedef __attribute__((ext_vector_type(8))) _Float16 f16x8;
typedef __attribute__((ext_vector_type(4))) float f32x4;
typedef __attribute__((ext_vector_type(16))) float f32x16;

__device__ __forceinline__ void split2(float f, __hip_bfloat16& h, __hip_bfloat16& l) {
  h = __float2bfloat16(f);
  l = __float2bfloat16(f - __bfloat162float(h));
}

__device__ __forceinline__ unsigned int packf16(float a, float b) {
  union { _Float16 h[2]; unsigned int u; } c;
  c.h[0] = (_Float16)a;  // RN casts: unbiased (RTZ pkrtz would bias softmax weights)
  c.h[1] = (_Float16)b;
  return c.u;
}

// ---------------------------------------------------------------------------
// Kernel W: pre-split weights fp32 -> bf16 hi/lo.  (wiolo now unused by proj
// but kept for layout stability; wohi/wolo feed out_proj.)
// ---------------------------------------------------------------------------
__global__ __launch_bounds__(256) void wconv_kernel(
    const float* __restrict__ wio, const float* __restrict__ wo,
    __hip_bfloat16* __restrict__ wiohi, __hip_bfloat16* __restrict__ wiolo,
    __hip_bfloat16* __restrict__ wohi, __hip_bfloat16* __restrict__ wolo) {
  const int g = blockIdx.x * 256 + threadIdx.x;
  const float* src;
  __hip_bfloat16 *dh, *dl;
  int i;
  if (g < 196608) { src = wio; dh = wiohi; dl = wiolo; i = g * 4; }
  else            { src = wo;  dh = wohi;  dl = wolo;  i = (g - 196608) * 4; }
  const float4 f = *(const float4*)(src + i);
  alignas(8) __hip_bfloat16 h[4], l[4];
  split2(f.x, h[0], l[0]); split2(f.y, h[1], l[1]);
  split2(f.z, h[2], l[2]); split2(f.w, h[3], l[3]);
  *(uint2*)(dh + i) = *(const uint2*)h;
  *(uint2*)(dl + i) = *(const uint2*)l;
}

// ---------------------------------------------------------------------------
// Kernel A: packed QKV projection via MFMA, hi/lo 2-pass (hh + lh; the hl
// term x_hi*w_lo is dropped -- its ~6e-4 q/k/v error attenuates to ~2e-5
// through attention).  Q epilogue folds the 0.125*log2e softmax scale and
// stores fp16; K stores fp16; V stores u = max(v+sh,eps)^p directly as fp16.
// ---------------------------------------------------------------------------
__global__ __launch_bounds__(256, 3) void proj_qkv_kernel(
    const float* __restrict__ xq, const float* __restrict__ xk,
    const float* __restrict__ xv, const __hip_bfloat16* __restrict__ whi,
    const float* __restrict__ bias, const float* __restrict__ pw,
    const float* __restrict__ sw,
    _Float16* __restrict__ qbuf, _Float16* __restrict__ kbuf,
    _Float16* __restrict__ ubuf) {
  __shared__ __hip_bfloat16 Xh[128][40];
  __shared__ __hip_bfloat16 Xl[128][40];
  __shared__ __hip_bfloat16 Wh[128][40];
  const int z = blockIdx.z;
  const int row0 = blockIdx.x * 128;
  const int col0 = blockIdx.y * 128;
  const float* __restrict__ xsrc = (z == 0) ? xq : (z == 1) ? xk : xv;
  const int tid = threadIdx.x;
  const int lane = tid & 63;
  const int wv = tid >> 6;
  const int lidx = lane & 15;
  const int quad = lane >> 4;
  const int srow = tid >> 1;
  const int scol = (tid & 1) * 16;

  f32x4 acc[2][8];
#pragma unroll
  for (int rt = 0; rt < 2; ++rt)
#pragma unroll
    for (int ct = 0; ct < 8; ++ct) acc[rt][ct] = (f32x4){0.f, 0.f, 0.f, 0.f};

  const int ar0 = wv * 32 + lidx;

  for (int kt = 0; kt < 16; ++kt) {
    const int k0 = kt * 32;
    {
      const float* xp = xsrc + (size_t)(row0 + srow) * E_DIM + k0 + scol;
      float f[16];
      *(float4*)&f[0]  = ((const float4*)xp)[0];
      *(float4*)&f[4]  = ((const float4*)xp)[1];
      *(float4*)&f[8]  = ((const float4*)xp)[2];
      *(float4*)&f[12] = ((const float4*)xp)[3];
      alignas(16) __hip_bfloat16 hi[16], lo[16];
#pragma unroll
      for (int j = 0; j < 16; ++j) split2(f[j], hi[j], lo[j]);
      *(uint4*)&Xh[srow][scol]     = ((const uint4*)hi)[0];
      *(uint4*)&Xh[srow][scol + 8] = ((const uint4*)hi)[1];
      *(uint4*)&Xl[srow][scol]     = ((const uint4*)lo)[0];
      *(uint4*)&Xl[srow][scol + 8] = ((const uint4*)lo)[1];
    }
    {
      const size_t wof = (size_t)(z * E_DIM + col0 + srow) * E_DIM + k0 + scol;
      *(uint4*)&Wh[srow][scol]     = ((const uint4*)(whi + wof))[0];
      *(uint4*)&Wh[srow][scol + 8] = ((const uint4*)(whi + wof))[1];
    }
    __syncthreads();

    const bf16x8 ah0 = *(const bf16x8*)&Xh[ar0][quad * 8];
    const bf16x8 ah1 = *(const bf16x8*)&Xh[ar0 + 16][quad * 8];
    const bf16x8 al0 = *(const bf16x8*)&Xl[ar0][quad * 8];
    const bf16x8 al1 = *(const bf16x8*)&Xl[ar0 + 16][quad * 8];
#pragma unroll
    for (int ct = 0; ct < 8; ++ct) {
      const bf16x8 bh = *(const bf16x8*)&Wh[ct * 16 + lidx][quad * 8];
      acc[0][ct] = __builtin_amdgcn_mfma_f32_16x16x32_bf16(ah0, bh, acc[0][ct], 0, 0, 0);
      acc[0][ct] = __builtin_amdgcn_mfma_f32_16x16x32_bf16(al0, bh, acc[0][ct], 0, 0, 0);
      acc[1][ct] = __builtin_amdgcn_mfma_f32_16x16x32_bf16(ah1, bh, acc[1][ct], 0, 0, 0);
      acc[1][ct] = __builtin_amdgcn_mfma_f32_16x16x32_bf16(al1, bh, acc[1][ct], 0, 0, 0);
    }
    __syncthreads();
  }

  if (z < 2) {
    _Float16* __restrict__ dst = (z == 0) ? qbuf : kbuf;
    const float scale = (z == 0) ? SC_Q : 1.0f;
    float bv[8];
#pragma unroll
    for (int ct = 0; ct < 8; ++ct) bv[ct] = bias[z * E_DIM + col0 + ct * 16 + lidx];
#pragma unroll
    for (int rt = 0; rt < 2; ++rt)
#pragma unroll
      for (int ct = 0; ct < 8; ++ct) {
        const int e = col0 + ct * 16 + lidx;
        const int h = e >> 6, d = e & 63;
#pragma unroll
        for (int reg = 0; reg < 4; ++reg) {
          const int R = row0 + wv * 32 + rt * 16 + quad * 4 + reg;
          const int lpos = R >> 2, nb = R & 3;
          dst[(((size_t)nb * N_HEADS + h) * L_SEQ + lpos) * H_DIM + d] =
              (_Float16)((acc[rt][ct][reg] + bv[ct]) * scale);
        }
      }
  } else {
    float bv[8], pv[8], sv[8];
#pragma unroll
    for (int ct = 0; ct < 8; ++ct) {
      const int e = col0 + ct * 16 + lidx;
      bv[ct] = bias[2 * E_DIM + e]; pv[ct] = pw[e]; sv[ct] = sw[e];
    }
#pragma unroll
    for (int rt = 0; rt < 2; ++rt)
#pragma unroll
      for (int ct = 0; ct < 8; ++ct) {
        const int e = col0 + ct * 16 + lidx;
        const int h = e >> 6, d = e & 63;
#pragma unroll
        for (int reg = 0; reg < 4; ++reg) {
          const int R = row0 + wv * 32 + rt * 16 + quad * 4 + reg;
          const int lpos = R >> 2, nb = R & 3;
          const float y = acc[rt][ct][reg] + bv[ct];
          const float vp = fmaxf(y + sv[ct], EPS_F);
          ubuf[(((size_t)nb * N_HEADS + h) * L_SEQ + lpos) * H_DIM + d] =
              (_Float16)__powf(vp, pv[ct]);
        }
      }
  }
}

// ---------------------------------------------------------------------------
// Kernel T: transpose u (n,h,l,d) fp16 -> u^T (n,h,d,l) fp16.
// ---------------------------------------------------------------------------
__global__ __launch_bounds__(256) void transp_kernel(
    const _Float16* __restrict__ u, _Float16* __restrict__ uT) {
  __shared__ _Float16 T[64][72];
  const int lt = blockIdx.x, h = blockIdx.y, nb = blockIdx.z;
  const int tid = threadIdx.x;
  const int r = tid >> 2;
  const int cb = (tid & 3) * 16;
  const size_t srcbase = ((size_t)nb * N_HEADS + h) * L_SEQ + lt * 64;
  {
    const _Float16* p = u + (srcbase + r) * H_DIM + cb;
    *(uint4*)&T[r][cb + 0] = ((const uint4*)p)[0];
    *(uint4*)&T[r][cb + 8] = ((const uint4*)p)[1];
  }
  __syncthreads();
  alignas(16) _Float16 hv[16];
#pragma unroll
  for (int j = 0; j < 16; ++j) hv[j] = T[cb + j][r];
  const size_t dst = (((size_t)nb * N_HEADS + h) * H_DIM + r) * L_SEQ + lt * 64 + cb;
  *(uint4*)(uT + dst)     = ((const uint4*)hv)[0];
  *(uint4*)(uT + dst + 8) = ((const uint4*)hv)[1];
}

// ---------------------------------------------------------------------------
// Kernel B: fp16 MFMA flash attention, S^T orientation (A=K, B=Q).
//
// v12 (barrier-free rework): v10/v11 proved (a) all K/U loads are L2-hits
// after the XCD remap (FETCH 70->12.8MB, dur unchanged) and (b) compute-path
// thinning works (permlane +10us).  Remaining ~45% dual-idle cycles are the
// two-barrier staging loop itself: 8 waves drain at B1, ride out the load
// window to B2, every iteration, at an LDS-capped 2 blocks/CU.  But L2
// residency voids the reason for LDS staging -- so drop it ENTIRELY:
//   Each wave is fully independent: 32 q-rows (q0 = qt*128 + w*32), loops
//   all 2048 s in 64-row steps, loading its 16 K/U f16x8 fragments per step
//   straight from global (L2, ~200cy, 3MB/XCD working set).  Fragment
//   addresses are v11's LDS-frag math with sr folded into s0 (verified
//   index-by-index).  NO __shared__, NO __syncthreads, no s-split, no
//   cross-wave reduction.  Races impossible; compiler is free to pipeline
//   loads across steps (budget 256 at (256,2), ~170 live, no spill; only
//   2 waves/SIMD are supplied so >128 regs costs nothing).
// L2 redundancy cost: 64 waves per (nb,h) re-read K/U -> ~1GB L2 traffic
// ~ 29us at aggregate L2 BW; MFMA floor ~20us.  Both << 87us.
// permlane32_swap (T12) + setprio (T5) kept from v11.
// Grid 512 x 256 thr (4 independent waves/block).
// ---------------------------------------------------------------------------
__global__ __launch_bounds__(256, 2) void attn_kernel(
    const _Float16* __restrict__ qbuf, const _Float16* __restrict__ kbuf,
    const _Float16* __restrict__ uT, const float* __restrict__ pw,
    const float* __restrict__ sw, __hip_bfloat16* __restrict__ ohhi,
    __hip_bfloat16* __restrict__ ohlo) {
  // XCD-clustered decode: f -> xcd = f&7 (dispatch round-robin); XCD x owns
  // heads [4x,4x+4) x all 16 q-tiles.  Bijective: f = ((hidx&3)*16+qt)*8+xcd.
  const int f = blockIdx.x;              // 0..511
  const int xcd = f & 7;
  const int j = f >> 3;                  // 0..63
  const int qt = j & 15;
  const int hidx = xcd * 4 + (j >> 4);   // 0..31
  const int h = hidx & 7, nb = hidx >> 3;
  const int tid = threadIdx.x;
  const int lane = tid & 63;
  const int w = tid >> 6;           // wave 0..3: independent q-subtile
  const int q0 = qt * 128 + w * 32;
  const int lm = lane & 31;
  const int kg = lane >> 5;         // k-group within MFMA operands
  const size_t headbase = ((size_t)nb * N_HEADS + h) * L_SEQ;
  const size_t dbase = ((size_t)nb * N_HEADS + h) * H_DIM;

  // Q B-frags from global: q = q0 + lm
  f16x8 bq[4];
#pragma unroll
  for (int kc = 0; kc < 4; ++kc)
    bq[kc] = *(const f16x8*)(qbuf +
        (headbase + q0 + lm) * H_DIM + kc * 16 + kg * 8);

  f32x16 o[2];  // [d-half mt2]
  o[0] = (f32x16)(0.f); o[1] = (f32x16)(0.f);
  float lsum = 0.f;

  const _Float16* __restrict__ kp0 = kbuf + (headbase + lm) * H_DIM;
  const _Float16* __restrict__ kp1 = kbuf + (headbase + 32 + lm) * H_DIM;
  const _Float16* __restrict__ up0 = uT + (dbase + lm) * L_SEQ;
  const _Float16* __restrict__ up1 = uT + (dbase + 32 + lm) * L_SEQ;

  for (int s0 = 0; s0 < L_SEQ; s0 += 64) {
    // ---- fragment loads straight from global (L2-resident) ----
    f16x8 ak0[4], ak1[4], au0[4], au1[4];
#pragma unroll
    for (int kc = 0; kc < 4; ++kc) {
      const int c = kc * 16 + kg * 8;
      ak0[kc] = *(const f16x8*)(kp0 + (size_t)s0 * H_DIM + c);
      ak1[kc] = *(const f16x8*)(kp1 + (size_t)s0 * H_DIM + c);
      au0[kc] = *(const f16x8*)(up0 + s0 + c);
      au1[kc] = *(const f16x8*)(up1 + s0 + c);
    }

    // ---- S^T: sc[mt], C-layout row = s_local, col = q (lane&31) ----
    f32x16 sc0 = (f32x16)(0.f), sc1 = (f32x16)(0.f);
    __builtin_amdgcn_s_setprio(1);
#pragma unroll
    for (int kc = 0; kc < 4; ++kc) {
      sc0 = __builtin_amdgcn_mfma_f32_32x32x16_f16(ak0[kc], bq[kc], sc0, 0, 0, 0);
      sc1 = __builtin_amdgcn_mfma_f32_32x32x16_f16(ak1[kc], bq[kc], sc1, 0, 0, 0);
    }
    __builtin_amdgcn_s_setprio(0);

    // ---- p = exp2(score); pack fp16 pairs; per-lane l partial sum ----
    unsigned int P2[2][4][2];
#pragma unroll
    for (int mt = 0; mt < 2; ++mt) {
      const f32x16& sc = mt ? sc1 : sc0;
#pragma unroll
      for (int g = 0; g < 4; ++g) {
        const float p0 = __builtin_amdgcn_exp2f(sc[4 * g + 0]);
        const float p1 = __builtin_amdgcn_exp2f(sc[4 * g + 1]);
        const float p2 = __builtin_amdgcn_exp2f(sc[4 * g + 2]);
        const float p3 = __builtin_amdgcn_exp2f(sc[4 * g + 3]);
        lsum += (p0 + p1) + (p2 + p3);
        P2[mt][g][0] = packf16(p0, p1);
        P2[mt][g][1] = packf16(p2, p3);
      }
    }

    // ---- PV: O^T += U^T @ P^T; P B-frags via permlane32_swap (T12) ----
    __builtin_amdgcn_s_setprio(1);
#pragma unroll
    for (int kc = 0; kc < 4; ++kc) {
      const int mt = kc >> 1;
      const int gx = (2 * kc) & 3, gy = (2 * kc + 1) & 3;
      unsigned int a0 = P2[mt][gx][0], b0 = P2[mt][gy][0];
      unsigned int a1 = P2[mt][gx][1], b1 = P2[mt][gy][1];
      asm("v_permlane32_swap_b32 %0, %1" : "+v"(a0), "+v"(b0));
      asm("v_permlane32_swap_b32 %0, %1" : "+v"(a1), "+v"(b1));
      union { unsigned int u[4]; f16x8 v; } bp;
      bp.u[0] = a0;  // j0..3: s = kc*16+kg*8+0..3
      bp.u[1] = a1;
      bp.u[2] = b0;  // j4..7: s = kc*16+kg*8+4..7
      bp.u[3] = b1;
      o[0] = __builtin_amdgcn_mfma_f32_32x32x16_f16(au0[kc], bp.v, o[0], 0, 0, 0);
      o[1] = __builtin_amdgcn_mfma_f32_32x32x16_f16(au1[kc], bp.v, o[1], 0, 0, 0);
    }
    __builtin_amdgcn_s_setprio(0);
  }

  // ---- epilogue: finish l across kg halves, GeM inverse, packed stores ----
  {
    const float l = lsum + __shfl_xor(lsum, 32);
    const float inv = 1.0f / l;
    const int qg = q0 + lm;
    const size_t base = ((size_t)qg * N_BATCH + nb) * E_DIM + h * H_DIM;
#pragma unroll
    for (int mt2 = 0; mt2 < 2; ++mt2)
#pragma unroll
      for (int g = 0; g < 4; ++g) {
        alignas(8) __hip_bfloat16 hb[4], lb[4];
#pragma unroll
        for (int i = 0; i < 4; ++i) {
          const int d = mt2 * 32 + 8 * g + 4 * kg + i;
          const int e = h * H_DIM + d;
          const float pooled = o[mt2][4 * g + i] * inv;
          const float val = __powf(fmaxf(pooled, EPS_F), 1.0f / pw[e]) - sw[e];
          split2(val, hb[i], lb[i]);
        }
        const int d0 = mt2 * 32 + 8 * g + 4 * kg;
        *(uint2*)(ohhi + base + d0) = *(const uint2*)hb;
        *(uint2*)(ohlo + base + d0) = *(const uint2*)lb;
      }
  }
}

// ---------------------------------------------------------------------------
// Kernel C: output projection via MFMA, hi/lo 3-pass.  (unchanged)
// ---------------------------------------------------------------------------
__global__ __launch_bounds__(256, 4) void out_proj_kernel(
    const __hip_bfloat16* __restrict__ xhi, const __hip_bfloat16* __restrict__ xlo,
    const __hip_bfloat16* __restrict__ whi, const __hip_bfloat16* __restrict__ wlo,
    const float* __restrict__ bias, float* __restrict__ out) {
  __shared__ __hip_bfloat16 Xh[128][40];
  __shared__ __hip_bfloat16 Xl[128][40];
  __shared__ __hip_bfloat16 Wh[64][40];
  __shared__ __hip_bfloat16 Wl[64][40];
  const int row0 = blockIdx.x * 128;
  const int col0 = blockIdx.y * 64;
  const int tid = threadIdx.x;
  const int lane = tid & 63;
  const int wv = tid >> 6;
  const int lidx = lane & 15;
  const int quad = lane >> 4;
  const int srow = tid >> 1;
  const int scol = (tid & 1) * 16;
  const int wrow = tid >> 2;
  const int wcol = (tid & 3) * 8;

  f32x4 acc[2][4];
#pragma unroll
  for (int rt = 0; rt < 2; ++rt)
#pragma unroll
    for (int ct = 0; ct < 4; ++ct) acc[rt][ct] = (f32x4){0.f, 0.f, 0.f, 0.f};

  const int ar0 = wv * 32 + lidx;

  for (int kt = 0; kt < 16; ++kt) {
    const int k0 = kt * 32;
    {
      const size_t xof = (size_t)(row0 + srow) * E_DIM + k0 + scol;
      *(uint4*)&Xh[srow][scol]     = ((const uint4*)(xhi + xof))[0];
      *(uint4*)&Xh[srow][scol + 8] = ((const uint4*)(xhi + xof))[1];
      *(uint4*)&Xl[srow][scol]     = ((const uint4*)(xlo + xof))[0];
      *(uint4*)&Xl[srow][scol + 8] = ((const uint4*)(xlo + xof))[1];
      const size_t wof = (size_t)(col0 + wrow) * E_DIM + k0 + wcol;
      *(uint4*)&Wh[wrow][wcol] = *(const uint4*)(whi + wof);
      *(uint4*)&Wl[wrow][wcol] = *(const uint4*)(wlo + wof);
    }
    __syncthreads();

    const bf16x8 ah0 = *(const bf16x8*)&Xh[ar0][quad * 8];
    const bf16x8 ah1 = *(const bf16x8*)&Xh[ar0 + 16][quad * 8];
    const bf16x8 al0 = *(const bf16x8*)&Xl[ar0][quad * 8];
    const bf16x8 al1 = *(const bf16x8*)&Xl[ar0 + 16][quad * 8];
#pragma unroll
    for (int ct = 0; ct < 4; ++ct) {
      const bf16x8 bh = *(const bf16x8*)&Wh[ct * 16 + lidx][quad * 8];
      const bf16x8 bl = *(const bf16x8*)&Wl[ct * 16 + lidx][quad * 8];
      acc[0][ct] = __builtin_amdgcn_mfma_f32_16x16x32_bf16(ah0, bh, acc[0][ct], 0, 0, 0);
      acc[0][ct] = __builtin_amdgcn_mfma_f32_16x16x32_bf16(al0, bh, acc[0][ct], 0, 0, 0);
      acc[0][ct] = __builtin_amdgcn_mfma_f32_16x16x32_bf16(ah0, bl, acc[0][ct], 0, 0, 0);
      acc[1][ct] = __builtin_amdgcn_mfma_f32_16x16x32_bf16(ah1, bh, acc[1][ct], 0, 0, 0);
      acc[1][ct] = __builtin_amdgcn_mfma_f32_16x16x32_bf16(al1, bh, acc[1][ct], 0, 0, 0);
      acc[1][ct] = __builtin_amdgcn_mfma_f32_16x16x32_bf16(ah1, bl, acc[1][ct], 0, 0, 0);
    }
    __syncthreads();
  }

  float bv[4];
#pragma unroll
  for (int ct = 0; ct < 4; ++ct) bv[ct] = bias[col0 + ct * 16 + lidx];
#pragma unroll
  for (int rt = 0; rt < 2; ++rt)
#pragma unroll
    for (int ct = 0; ct < 4; ++ct) {
      const int c = col0 + ct * 16 + lidx;
#pragma unroll
      for (int reg = 0; reg < 4; ++reg) {
        const int R = row0 + wv * 32 + rt * 16 + quad * 4 + reg;
        out[(size_t)R * E_DIM + c] = acc[rt][ct][reg] + bv[ct];
      }
    }
}

extern "C" void kernel_launch(void* const* d_in, const int* in_sizes, int n_in,
                              void* d_out, int out_size, void* d_ws, size_t ws_size,
                              hipStream_t stream) {
  const float* q_in = (const float*)d_in[0];
  const float* k_in = (const float*)d_in[1];
  const float* v_in = (const float*)d_in[2];
  const float* wio  = (const float*)d_in[3];
  const float* bio  = (const float*)d_in[4];
  const float* wo   = (const float*)d_in[5];
  const float* bo   = (const float*)d_in[6];
  const float* pw   = (const float*)d_in[7];
  const float* sw   = (const float*)d_in[8];

  // Workspace layout unchanged (ubuf region now holds fp16 u in its first
  // half; ohhi/ohlo alias it after transp consumes u).
  const size_t NE = (size_t)N_ROWS * E_DIM;
  _Float16* qbuf = (_Float16*)d_ws;
  _Float16* kbuf = qbuf + NE;
  float* ubuf = (float*)(kbuf + NE);
  _Float16* uT = (_Float16*)(ubuf + NE);
  __hip_bfloat16* wiohi = (__hip_bfloat16*)(uT + NE);
  __hip_bfloat16* wiolo = wiohi + 786432;
  __hip_bfloat16* wohi  = wiolo + 786432;
  __hip_bfloat16* wolo  = wohi + 262144;
  __hip_bfloat16* ohhi = (__hip_bfloat16*)ubuf;  // alias: ubuf dead after transp
  __hip_bfloat16* ohlo = ohhi + NE;

  wconv_kernel<<<dim3(1024), 256, 0, stream>>>(wio, wo, wiohi, wiolo, wohi, wolo);
  proj_qkv_kernel<<<dim3(64, 4, 3), 256, 0, stream>>>(q_in, k_in, v_in, wiohi,
                                                      bio, pw, sw, qbuf, kbuf,
                                                      (_Float16*)ubuf);
  transp_kernel<<<dim3(32, 8, 4), 256, 0, stream>>>((const _Float16*)ubuf, uT);
  attn_kernel<<<dim3(512), 256, 0, stream>>>(qbuf, kbuf, uT, pw, sw,
                                             ohhi, ohlo);
  out_proj_kernel<<<dim3(64, 8), 256, 0, stream>>>(ohhi, ohlo, wohi, wolo,
                                                   bo, (float*)d_out);
}

// Round 13
// 271.374 us; speedup vs baseline: 1.5510x; 1.5510x over previous
//
#include <hip/hip_runtime.h>
#include <hip/hip_bf16.h>

// Problem constants (L,N,E,H,D) = (2048,4,512,8,64)
#define E_DIM 512
#define N_BATCH 4
#define L_SEQ 2048
#define N_HEADS 8
#define H_DIM 64
#define N_ROWS (L_SEQ * N_BATCH) /* 8192 */
#define EPS_F 1e-6f
#define SC_Q 0.18033688f  /* 0.125 * log2(e): scores come out in log2 space */

typedef __attribute__((ext_vector_type(8))) short bf16x8;
typedef __attribute__((ext_vector_type(8))) _Float16 f16x8;
typedef __attribute__((ext_vector_type(4))) float f32x4;
typedef __attribute__((ext_vector_type(16))) float f32x16;

__device__ __forceinline__ void split2(float f, __hip_bfloat16& h, __hip_bfloat16& l) {
  h = __float2bfloat16(f);
  l = __float2bfloat16(f - __bfloat162float(h));
}

__device__ __forceinline__ unsigned int packf16(float a, float b) {
  union { _Float16 h[2]; unsigned int u; } c;
  c.h[0] = (_Float16)a;  // RN casts: unbiased (RTZ pkrtz would bias softmax weights)
  c.h[1] = (_Float16)b;
  return c.u;
}

// ---------------------------------------------------------------------------
// Kernel W: pre-split weights fp32 -> bf16 hi/lo.  (wiolo now unused by proj
// but kept for layout stability; wohi/wolo feed out_proj.)
// ---------------------------------------------------------------------------
__global__ __launch_bounds__(256) void wconv_kernel(
    const float* __restrict__ wio, const float* __restrict__ wo,
    __hip_bfloat16* __restrict__ wiohi, __hip_bfloat16* __restrict__ wiolo,
    __hip_bfloat16* __restrict__ wohi, __hip_bfloat16* __restrict__ wolo) {
  const int g = blockIdx.x * 256 + threadIdx.x;
  const float* src;
  __hip_bfloat16 *dh, *dl;
  int i;
  if (g < 196608) { src = wio; dh = wiohi; dl = wiolo; i = g * 4; }
  else            { src = wo;  dh = wohi;  dl = wolo;  i = (g - 196608) * 4; }
  const float4 f = *(const float4*)(src + i);
  alignas(8) __hip_bfloat16 h[4], l[4];
  split2(f.x, h[0], l[0]); split2(f.y, h[1], l[1]);
  split2(f.z, h[2], l[2]); split2(f.w, h[3], l[3]);
  *(uint2*)(dh + i) = *(const uint2*)h;
  *(uint2*)(dl + i) = *(const uint2*)l;
}

// ---------------------------------------------------------------------------
// Kernel A: packed QKV projection via MFMA, hi/lo 2-pass (hh + lh).  Q folds
// the softmax scale, stores fp16; K fp16; V stores u = max(v+sh,eps)^p fp16.
//
// v13: proj surfaced as the largest kernel (173us this build; MfmaUtil 5.7%,
// Occ 15.6% -- same 2-barrier window disease attn had pre-v6).  Apply v6's
// proven transform: stage TWO k-slices per window (Xh0/Xl0/Wh0 + Xh1/Xl1/Wh1,
// identical shapes/strides/thread patterns), compute both, loop 16 -> 8.
// Halves barrier+window count.  LDS 30.7->61.4KB -> 2 blocks/CU (measured
// occupancy says <=2 were resident anyway).  Compute body via lambda with
// static buffer refs (rule #20 safe; v6 precedent).
// ---------------------------------------------------------------------------
__global__ __launch_bounds__(256, 3) void proj_qkv_kernel(
    const float* __restrict__ xq, const float* __restrict__ xk,
    const float* __restrict__ xv, const __hip_bfloat16* __restrict__ whi,
    const float* __restrict__ bias, const float* __restrict__ pw,
    const float* __restrict__ sw,
    _Float16* __restrict__ qbuf, _Float16* __restrict__ kbuf,
    _Float16* __restrict__ ubuf) {
  __shared__ __hip_bfloat16 Xh0[128][40];
  __shared__ __hip_bfloat16 Xl0[128][40];
  __shared__ __hip_bfloat16 Wh0[128][40];
  __shared__ __hip_bfloat16 Xh1[128][40];
  __shared__ __hip_bfloat16 Xl1[128][40];
  __shared__ __hip_bfloat16 Wh1[128][40];
  const int z = blockIdx.z;
  const int row0 = blockIdx.x * 128;
  const int col0 = blockIdx.y * 128;
  const float* __restrict__ xsrc = (z == 0) ? xq : (z == 1) ? xk : xv;
  const int tid = threadIdx.x;
  const int lane = tid & 63;
  const int wv = tid >> 6;
  const int lidx = lane & 15;
  const int quad = lane >> 4;
  const int srow = tid >> 1;
  const int scol = (tid & 1) * 16;

  f32x4 acc[2][8];
#pragma unroll
  for (int rt = 0; rt < 2; ++rt)
#pragma unroll
    for (int ct = 0; ct < 8; ++ct) acc[rt][ct] = (f32x4){0.f, 0.f, 0.f, 0.f};

  const int ar0 = wv * 32 + lidx;

  // stage one 32-wide k-slice (proven v1-v11 pattern, parameterized by dst)
  auto stage = [&](int k0, __hip_bfloat16 (&Xh)[128][40],
                   __hip_bfloat16 (&Xl)[128][40], __hip_bfloat16 (&Wh)[128][40]) {
    {
      const float* xp = xsrc + (size_t)(row0 + srow) * E_DIM + k0 + scol;
      float f[16];
      *(float4*)&f[0]  = ((const float4*)xp)[0];
      *(float4*)&f[4]  = ((const float4*)xp)[1];
      *(float4*)&f[8]  = ((const float4*)xp)[2];
      *(float4*)&f[12] = ((const float4*)xp)[3];
      alignas(16) __hip_bfloat16 hi[16], lo[16];
#pragma unroll
      for (int j = 0; j < 16; ++j) split2(f[j], hi[j], lo[j]);
      *(uint4*)&Xh[srow][scol]     = ((const uint4*)hi)[0];
      *(uint4*)&Xh[srow][scol + 8] = ((const uint4*)hi)[1];
      *(uint4*)&Xl[srow][scol]     = ((const uint4*)lo)[0];
      *(uint4*)&Xl[srow][scol + 8] = ((const uint4*)lo)[1];
    }
    {
      const size_t wof = (size_t)(z * E_DIM + col0 + srow) * E_DIM + k0 + scol;
      *(uint4*)&Wh[srow][scol]     = ((const uint4*)(whi + wof))[0];
      *(uint4*)&Wh[srow][scol + 8] = ((const uint4*)(whi + wof))[1];
    }
  };

  // compute one staged 32-wide k-slice (verbatim v1-v11 body)
  auto compute = [&](const __hip_bfloat16 (&Xh)[128][40],
                     const __hip_bfloat16 (&Xl)[128][40],
                     const __hip_bfloat16 (&Wh)[128][40]) {
    const bf16x8 ah0 = *(const bf16x8*)&Xh[ar0][quad * 8];
    const bf16x8 ah1 = *(const bf16x8*)&Xh[ar0 + 16][quad * 8];
    const bf16x8 al0 = *(const bf16x8*)&Xl[ar0][quad * 8];
    const bf16x8 al1 = *(const bf16x8*)&Xl[ar0 + 16][quad * 8];
#pragma unroll
    for (int ct = 0; ct < 8; ++ct) {
      const bf16x8 bh = *(const bf16x8*)&Wh[ct * 16 + lidx][quad * 8];
      acc[0][ct] = __builtin_amdgcn_mfma_f32_16x16x32_bf16(ah0, bh, acc[0][ct], 0, 0, 0);
      acc[0][ct] = __builtin_amdgcn_mfma_f32_16x16x32_bf16(al0, bh, acc[0][ct], 0, 0, 0);
      acc[1][ct] = __builtin_amdgcn_mfma_f32_16x16x32_bf16(ah1, bh, acc[1][ct], 0, 0, 0);
      acc[1][ct] = __builtin_amdgcn_mfma_f32_16x16x32_bf16(al1, bh, acc[1][ct], 0, 0, 0);
    }
  };

  for (int it = 0; it < 8; ++it) {
    const int k0 = it * 64;
    stage(k0,      Xh0, Xl0, Wh0);
    stage(k0 + 32, Xh1, Xl1, Wh1);
    __syncthreads();
    compute(Xh0, Xl0, Wh0);
    compute(Xh1, Xl1, Wh1);
    __syncthreads();
  }

  if (z < 2) {
    _Float16* __restrict__ dst = (z == 0) ? qbuf : kbuf;
    const float scale = (z == 0) ? SC_Q : 1.0f;
    float bv[8];
#pragma unroll
    for (int ct = 0; ct < 8; ++ct) bv[ct] = bias[z * E_DIM + col0 + ct * 16 + lidx];
#pragma unroll
    for (int rt = 0; rt < 2; ++rt)
#pragma unroll
      for (int ct = 0; ct < 8; ++ct) {
        const int e = col0 + ct * 16 + lidx;
        const int h = e >> 6, d = e & 63;
#pragma unroll
        for (int reg = 0; reg < 4; ++reg) {
          const int R = row0 + wv * 32 + rt * 16 + quad * 4 + reg;
          const int lpos = R >> 2, nb = R & 3;
          dst[(((size_t)nb * N_HEADS + h) * L_SEQ + lpos) * H_DIM + d] =
              (_Float16)((acc[rt][ct][reg] + bv[ct]) * scale);
        }
      }
  } else {
    float bv[8], pv[8], sv[8];
#pragma unroll
    for (int ct = 0; ct < 8; ++ct) {
      const int e = col0 + ct * 16 + lidx;
      bv[ct] = bias[2 * E_DIM + e]; pv[ct] = pw[e]; sv[ct] = sw[e];
    }
#pragma unroll
    for (int rt = 0; rt < 2; ++rt)
#pragma unroll
      for (int ct = 0; ct < 8; ++ct) {
        const int e = col0 + ct * 16 + lidx;
        const int h = e >> 6, d = e & 63;
#pragma unroll
        for (int reg = 0; reg < 4; ++reg) {
          const int R = row0 + wv * 32 + rt * 16 + quad * 4 + reg;
          const int lpos = R >> 2, nb = R & 3;
          const float y = acc[rt][ct][reg] + bv[ct];
          const float vp = fmaxf(y + sv[ct], EPS_F);
          ubuf[(((size_t)nb * N_HEADS + h) * L_SEQ + lpos) * H_DIM + d] =
              (_Float16)__powf(vp, pv[ct]);
        }
      }
  }
}

// ---------------------------------------------------------------------------
// Kernel T: transpose u (n,h,l,d) fp16 -> u^T (n,h,d,l) fp16.
// ---------------------------------------------------------------------------
__global__ __launch_bounds__(256) void transp_kernel(
    const _Float16* __restrict__ u, _Float16* __restrict__ uT) {
  __shared__ _Float16 T[64][72];
  const int lt = blockIdx.x, h = blockIdx.y, nb = blockIdx.z;
  const int tid = threadIdx.x;
  const int r = tid >> 2;
  const int cb = (tid & 3) * 16;
  const size_t srcbase = ((size_t)nb * N_HEADS + h) * L_SEQ + lt * 64;
  {
    const _Float16* p = u + (srcbase + r) * H_DIM + cb;
    *(uint4*)&T[r][cb + 0] = ((const uint4*)p)[0];
    *(uint4*)&T[r][cb + 8] = ((const uint4*)p)[1];
  }
  __syncthreads();
  alignas(16) _Float16 hv[16];
#pragma unroll
  for (int j = 0; j < 16; ++j) hv[j] = T[cb + j][r];
  const size_t dst = (((size_t)nb * N_HEADS + h) * H_DIM + r) * L_SEQ + lt * 64 + cb;
  *(uint4*)(uT + dst)     = ((const uint4*)hv)[0];
  *(uint4*)(uT + dst + 8) = ((const uint4*)hv)[1];
}

// ---------------------------------------------------------------------------
// Kernel B: fp16 MFMA flash attention (v11 champion, verbatim).  S^T
// orientation (A=K, B=Q); P in B-operand layout via permlane32_swap (T12);
// setprio around MFMA clusters (T5); XCD-clustered decode (T1); 256-row
// double window, two-barrier ordering; cross-s-group LDS reduction.
// v12's barrier-free direct-L2 variant REGRESSED (~2x): per-wave fragment
// loads exposed L2 latency at 2 waves/SIMD + 64x redundant panel reads.
// LDS staging amortizes exactly that -- direction closed.
// Grid 512 x 256 thr.
// ---------------------------------------------------------------------------
__global__ __launch_bounds__(256, 2) void attn_kernel(
    const _Float16* __restrict__ qbuf, const _Float16* __restrict__ kbuf,
    const _Float16* __restrict__ uT, const float* __restrict__ pw,
    const float* __restrict__ sw, __hip_bfloat16* __restrict__ ohhi,
    __hip_bfloat16* __restrict__ ohlo) {
  __shared__ union {
    struct { _Float16 Ks0[128][72]; _Float16 Us0[64][136];
             _Float16 Ks1[128][72]; _Float16 Us1[64][136]; } st;
    struct { float A[2][64][64]; float lA[2][2][64]; } red;
  } sm;
  // XCD-clustered decode: f -> xcd = f&7 (dispatch round-robin); XCD x owns
  // heads [4x,4x+4) x all 16 q-tiles.  Bijective: f = ((hidx&3)*16+qt)*8+xcd.
  const int f = blockIdx.x;              // 0..511
  const int xcd = f & 7;
  const int j = f >> 3;                  // 0..63
  const int qt = j & 15;
  const int hidx = xcd * 4 + (j >> 4);   // 0..31
  const int h = hidx & 7, nb = hidx >> 3;
  const int q0 = qt * 128;
  const int tid = threadIdx.x;
  const int lane = tid & 63;
  const int w = tid >> 6;           // wave 0..3
  const int wv = w & 1;             // q-half of the block tile
  const int sg = w >> 1;            // s-group 0..1
  const int lm = lane & 31;
  const int kg = lane >> 5;         // k-group within MFMA operands
  const int srow = tid >> 1;        // K staging row 0..127
  const int scb = (tid & 1) * 32;   // K staging col base (fp16 units)
  const int urow = tid >> 2;        // U staging row (d) 0..63
  const int ucb = (tid & 3) * 32;   // U staging col base (s units)
  const size_t headbase = ((size_t)nb * N_HEADS + h) * L_SEQ;
  const size_t dbase = ((size_t)nb * N_HEADS + h) * H_DIM;

  // hoist Q B-frags straight from global (no Q LDS): q(nt) = q0+wv*64+nt*32+lm
  f16x8 bq[2][4];
#pragma unroll
  for (int nt = 0; nt < 2; ++nt)
#pragma unroll
    for (int kc = 0; kc < 4; ++kc)
      bq[nt][kc] = *(const f16x8*)(qbuf +
          (headbase + q0 + wv * 64 + nt * 32 + lm) * H_DIM + kc * 16 + kg * 8);

  f32x16 o[2][2];  // [q-half nt][d-half mt2]
  o[0][0] = (f32x16)(0.f); o[0][1] = (f32x16)(0.f);
  o[1][0] = (f32x16)(0.f); o[1][1] = (f32x16)(0.f);
  float lsum[2] = {0.f, 0.f};

  // compute one 64-row s-slice from a staged half-tile
  auto do_half = [&](const _Float16 (&Ks)[128][72], const _Float16 (&Us)[64][136]) {
    const int sr = sg * 64;  // this wave's s-rows within the staged 128

    // ---- S^T: sc[nt][mt], C-layout row = s_local, col = q (lane&31) ----
    f32x16 sc[2][2];
    sc[0][0] = (f32x16)(0.f); sc[0][1] = (f32x16)(0.f);
    sc[1][0] = (f32x16)(0.f); sc[1][1] = (f32x16)(0.f);
    __builtin_amdgcn_s_setprio(1);
#pragma unroll
    for (int kc = 0; kc < 4; ++kc) {
      const f16x8 ak0 = *(const f16x8*)&Ks[sr + lm][kc * 16 + kg * 8];
      const f16x8 ak1 = *(const f16x8*)&Ks[sr + 32 + lm][kc * 16 + kg * 8];
      sc[0][0] = __builtin_amdgcn_mfma_f32_32x32x16_f16(ak0, bq[0][kc], sc[0][0], 0, 0, 0);
      sc[0][1] = __builtin_amdgcn_mfma_f32_32x32x16_f16(ak1, bq[0][kc], sc[0][1], 0, 0, 0);
      sc[1][0] = __builtin_amdgcn_mfma_f32_32x32x16_f16(ak0, bq[1][kc], sc[1][0], 0, 0, 0);
      sc[1][1] = __builtin_amdgcn_mfma_f32_32x32x16_f16(ak1, bq[1][kc], sc[1][1], 0, 0, 0);
    }
    __builtin_amdgcn_s_setprio(0);

    // ---- p = exp2(score); pack fp16 pairs; per-lane l partial sum ----
    unsigned int P2[2][2][4][2];
#pragma unroll
    for (int nt = 0; nt < 2; ++nt)
#pragma unroll
      for (int mt = 0; mt < 2; ++mt)
#pragma unroll
        for (int g = 0; g < 4; ++g) {
          const float p0 = __builtin_amdgcn_exp2f(sc[nt][mt][4 * g + 0]);
          const float p1 = __builtin_amdgcn_exp2f(sc[nt][mt][4 * g + 1]);
          const float p2 = __builtin_amdgcn_exp2f(sc[nt][mt][4 * g + 2]);
          const float p3 = __builtin_amdgcn_exp2f(sc[nt][mt][4 * g + 3]);
          lsum[nt] += (p0 + p1) + (p2 + p3);
          P2[nt][mt][g][0] = packf16(p0, p1);
          P2[nt][mt][g][1] = packf16(p2, p3);
        }

    // ---- PV: O^T += U^T @ P^T; P B-frags via permlane32_swap (T12).
    //      v_permlane32_swap_b32 a,b: a[32..63] <-> b[0..31].  With
    //      a=x0,b=y0: a' = (l<32 ? x0[l] : y0[l-32]) == old bp.u[0];
    //      b' = (l<32 ? x0[l+32] : y0[l]) == old bp.u[2].  Bit-identical
    //      to the shfl_xor+cndmask network it replaces. ----
    __builtin_amdgcn_s_setprio(1);
#pragma unroll
    for (int kc = 0; kc < 4; ++kc) {
      const int mt = kc >> 1;
      const f16x8 au0 = *(const f16x8*)&Us[lm][sr + kc * 16 + kg * 8];
      const f16x8 au1 = *(const f16x8*)&Us[32 + lm][sr + kc * 16 + kg * 8];
#pragma unroll
      for (int nt = 0; nt < 2; ++nt) {
        const int gx = (2 * kc) & 3, gy = (2 * kc + 1) & 3;
        unsigned int a0 = P2[nt][mt][gx][0], b0 = P2[nt][mt][gy][0];
        unsigned int a1 = P2[nt][mt][gx][1], b1 = P2[nt][mt][gy][1];
        asm("v_permlane32_swap_b32 %0, %1" : "+v"(a0), "+v"(b0));
        asm("v_permlane32_swap_b32 %0, %1" : "+v"(a1), "+v"(b1));
        union { unsigned int u[4]; f16x8 v; } bp;
        bp.u[0] = a0;  // j0..3: s = kc*16+kg*8+0..3
        bp.u[1] = a1;
        bp.u[2] = b0;  // j4..7: s = kc*16+kg*8+4..7
        bp.u[3] = b1;
        o[nt][0] = __builtin_amdgcn_mfma_f32_32x32x16_f16(au0, bp.v, o[nt][0], 0, 0, 0);
        o[nt][1] = __builtin_amdgcn_mfma_f32_32x32x16_f16(au1, bp.v, o[nt][1], 0, 0, 0);
      }
    }
    __builtin_amdgcn_s_setprio(0);
  };

  for (int it = 0; it < 8; ++it) {
    const int s0 = it * 256;
    __syncthreads();  // B1: prior window's frag reads complete
    {
      const _Float16* kp = kbuf + (headbase + s0 + srow) * H_DIM + scb;
      *(uint4*)&sm.st.Ks0[srow][scb + 0]  = ((const uint4*)kp)[0];
      *(uint4*)&sm.st.Ks0[srow][scb + 8]  = ((const uint4*)kp)[1];
      *(uint4*)&sm.st.Ks0[srow][scb + 16] = ((const uint4*)kp)[2];
      *(uint4*)&sm.st.Ks0[srow][scb + 24] = ((const uint4*)kp)[3];
      const _Float16* kq = kbuf + (headbase + s0 + 128 + srow) * H_DIM + scb;
      *(uint4*)&sm.st.Ks1[srow][scb + 0]  = ((const uint4*)kq)[0];
      *(uint4*)&sm.st.Ks1[srow][scb + 8]  = ((const uint4*)kq)[1];
      *(uint4*)&sm.st.Ks1[srow][scb + 16] = ((const uint4*)kq)[2];
      *(uint4*)&sm.st.Ks1[srow][scb + 24] = ((const uint4*)kq)[3];
      const _Float16* up = uT + (dbase + urow) * L_SEQ + s0 + ucb;
      *(uint4*)&sm.st.Us0[urow][ucb + 0]  = ((const uint4*)up)[0];
      *(uint4*)&sm.st.Us0[urow][ucb + 8]  = ((const uint4*)up)[1];
      *(uint4*)&sm.st.Us0[urow][ucb + 16] = ((const uint4*)up)[2];
      *(uint4*)&sm.st.Us0[urow][ucb + 24] = ((const uint4*)up)[3];
      const _Float16* uq = up + 128;
      *(uint4*)&sm.st.Us1[urow][ucb + 0]  = ((const uint4*)uq)[0];
      *(uint4*)&sm.st.Us1[urow][ucb + 8]  = ((const uint4*)uq)[1];
      *(uint4*)&sm.st.Us1[urow][ucb + 16] = ((const uint4*)uq)[2];
      *(uint4*)&sm.st.Us1[urow][ucb + 24] = ((const uint4*)uq)[3];
    }
    __syncthreads();  // B2: staged 256-row tile visible to all waves

    do_half(sm.st.Ks0, sm.st.Us0);
    do_half(sm.st.Ks1, sm.st.Us1);
  }

  // ---- cross-s-group reduction in LDS: sg1 publishes (o, lsum), sg0
  //      accumulates.  XOR-swizzled float4 slots keep accesses at the
  //      8-dwords/bank wave64 minimum (conflict-free).  ----
  float* redA = &sm.red.A[0][0][0];
  float* lrA = &sm.red.lA[0][0][0];

  __syncthreads();  // loop's trailing frag reads complete before LDS reuse
  if (sg == 1) {
#pragma unroll
    for (int nt = 0; nt < 2; ++nt) {
      lrA[(wv * 2 + nt) * 64 + lane] = lsum[nt];
#pragma unroll
      for (int mt2 = 0; mt2 < 2; ++mt2)
#pragma unroll
        for (int g = 0; g < 4; ++g) {
          const int i4 = ((nt * 2 + mt2) * 4 + g) ^ (lane & 7);
          float4 v = {o[nt][mt2][4 * g + 0], o[nt][mt2][4 * g + 1],
                      o[nt][mt2][4 * g + 2], o[nt][mt2][4 * g + 3]};
          *(float4*)(redA + ((size_t)(wv * 64 + lane)) * 64 + i4 * 4) = v;
        }
    }
  }
  __syncthreads();
  if (sg == 1) return;  // sg0 past this point; no further barriers
#pragma unroll
  for (int nt = 0; nt < 2; ++nt) {
    lsum[nt] += lrA[(wv * 2 + nt) * 64 + lane];
#pragma unroll
    for (int mt2 = 0; mt2 < 2; ++mt2)
#pragma unroll
      for (int g = 0; g < 4; ++g) {
        const int i4 = ((nt * 2 + mt2) * 4 + g) ^ (lane & 7);
        const float4 v =
            *(const float4*)(redA + ((size_t)(wv * 64 + lane)) * 64 + i4 * 4);
        o[nt][mt2][4 * g + 0] += v.x; o[nt][mt2][4 * g + 1] += v.y;
        o[nt][mt2][4 * g + 2] += v.z; o[nt][mt2][4 * g + 3] += v.w;
      }
  }

  // ---- epilogue: finish l across kg halves, GeM inverse, packed stores ----
#pragma unroll
  for (int nt = 0; nt < 2; ++nt) {
    const float l = lsum[nt] + __shfl_xor(lsum[nt], 32);
    const float inv = 1.0f / l;
    const int qg = q0 + wv * 64 + nt * 32 + lm;
    const size_t base = ((size_t)qg * N_BATCH + nb) * E_DIM + h * H_DIM;
#pragma unroll
    for (int mt2 = 0; mt2 < 2; ++mt2)
#pragma unroll
      for (int g = 0; g < 4; ++g) {
        alignas(8) __hip_bfloat16 hb[4], lb[4];
#pragma unroll
        for (int i = 0; i < 4; ++i) {
          const int d = mt2 * 32 + 8 * g + 4 * kg + i;
          const int e = h * H_DIM + d;
          const float pooled = o[nt][mt2][4 * g + i] * inv;
          const float val = __powf(fmaxf(pooled, EPS_F), 1.0f / pw[e]) - sw[e];
          split2(val, hb[i], lb[i]);
        }
        const int d0 = mt2 * 32 + 8 * g + 4 * kg;
        *(uint2*)(ohhi + base + d0) = *(const uint2*)hb;
        *(uint2*)(ohlo + base + d0) = *(const uint2*)lb;
      }
  }
}

// ---------------------------------------------------------------------------
// Kernel C: output projection via MFMA, hi/lo 3-pass.  (unchanged)
// ---------------------------------------------------------------------------
__global__ __launch_bounds__(256, 4) void out_proj_kernel(
    const __hip_bfloat16* __restrict__ xhi, const __hip_bfloat16* __restrict__ xlo,
    const __hip_bfloat16* __restrict__ whi, const __hip_bfloat16* __restrict__ wlo,
    const float* __restrict__ bias, float* __restrict__ out) {
  __shared__ __hip_bfloat16 Xh[128][40];
  __shared__ __hip_bfloat16 Xl[128][40];
  __shared__ __hip_bfloat16 Wh[64][40];
  __shared__ __hip_bfloat16 Wl[64][40];
  const int row0 = blockIdx.x * 128;
  const int col0 = blockIdx.y * 64;
  const int tid = threadIdx.x;
  const int lane = tid & 63;
  const int wv = tid >> 6;
  const int lidx = lane & 15;
  const int quad = lane >> 4;
  const int srow = tid >> 1;
  const int scol = (tid & 1) * 16;
  const int wrow = tid >> 2;
  const int wcol = (tid & 3) * 8;

  f32x4 acc[2][4];
#pragma unroll
  for (int rt = 0; rt < 2; ++rt)
#pragma unroll
    for (int ct = 0; ct < 4; ++ct) acc[rt][ct] = (f32x4){0.f, 0.f, 0.f, 0.f};

  const int ar0 = wv * 32 + lidx;

  for (int kt = 0; kt < 16; ++kt) {
    const int k0 = kt * 32;
    {
      const size_t xof = (size_t)(row0 + srow) * E_DIM + k0 + scol;
      *(uint4*)&Xh[srow][scol]     = ((const uint4*)(xhi + xof))[0];
      *(uint4*)&Xh[srow][scol + 8] = ((const uint4*)(xhi + xof))[1];
      *(uint4*)&Xl[srow][scol]     = ((const uint4*)(xlo + xof))[0];
      *(uint4*)&Xl[srow][scol + 8] = ((const uint4*)(xlo + xof))[1];
      const size_t wof = (size_t)(col0 + wrow) * E_DIM + k0 + wcol;
      *(uint4*)&Wh[wrow][wcol] = *(const uint4*)(whi + wof);
      *(uint4*)&Wl[wrow][wcol] = *(const uint4*)(wlo + wof);
    }
    __syncthreads();

    const bf16x8 ah0 = *(const bf16x8*)&Xh[ar0][quad * 8];
    const bf16x8 ah1 = *(const bf16x8*)&Xh[ar0 + 16][quad * 8];
    const bf16x8 al0 = *(const bf16x8*)&Xl[ar0][quad * 8];
    const bf16x8 al1 = *(const bf16x8*)&Xl[ar0 + 16][quad * 8];
#pragma unroll
    for (int ct = 0; ct < 4; ++ct) {
      const bf16x8 bh = *(const bf16x8*)&Wh[ct * 16 + lidx][quad * 8];
      const bf16x8 bl = *(const bf16x8*)&Wl[ct * 16 + lidx][quad * 8];
      acc[0][ct] = __builtin_amdgcn_mfma_f32_16x16x32_bf16(ah0, bh, acc[0][ct], 0, 0, 0);
      acc[0][ct] = __builtin_amdgcn_mfma_f32_16x16x32_bf16(al0, bh, acc[0][ct], 0, 0, 0);
      acc[0][ct] = __builtin_amdgcn_mfma_f32_16x16x32_bf16(ah0, bl, acc[0][ct], 0, 0, 0);
      acc[1][ct] = __builtin_amdgcn_mfma_f32_16x16x32_bf16(ah1, bh, acc[1][ct], 0, 0, 0);
      acc[1][ct] = __builtin_amdgcn_mfma_f32_16x16x32_bf16(al1, bh, acc[1][ct], 0, 0, 0);
      acc[1][ct] = __builtin_amdgcn_mfma_f32_16x16x32_bf16(ah1, bl, acc[1][ct], 0, 0, 0);
    }
    __syncthreads();
  }

  float bv[4];
#pragma unroll
  for (int ct = 0; ct < 4; ++ct) bv[ct] = bias[col0 + ct * 16 + lidx];
#pragma unroll
  for (int rt = 0; rt < 2; ++rt)
#pragma unroll
    for (int ct = 0; ct < 4; ++ct) {
      const int c = col0 + ct * 16 + lidx;
#pragma unroll
      for (int reg = 0; reg < 4; ++reg) {
        const int R = row0 + wv * 32 + rt * 16 + quad * 4 + reg;
        out[(size_t)R * E_DIM + c] = acc[rt][ct][reg] + bv[ct];
      }
    }
}

extern "C" void kernel_launch(void* const* d_in, const int* in_sizes, int n_in,
                              void* d_out, int out_size, void* d_ws, size_t ws_size,
                              hipStream_t stream) {
  const float* q_in = (const float*)d_in[0];
  const float* k_in = (const float*)d_in[1];
  const float* v_in = (const float*)d_in[2];
  const float* wio  = (const float*)d_in[3];
  const float* bio  = (const float*)d_in[4];
  const float* wo   = (const float*)d_in[5];
  const float* bo   = (const float*)d_in[6];
  const float* pw   = (const float*)d_in[7];
  const float* sw   = (const float*)d_in[8];

  // Workspace layout unchanged (ubuf region holds fp16 u in its first half;
  // ohhi/ohlo alias it after transp consumes u).
  const size_t NE = (size_t)N_ROWS * E_DIM;
  _Float16* qbuf = (_Float16*)d_ws;
  _Float16* kbuf = qbuf + NE;
  float* ubuf = (float*)(kbuf + NE);
  _Float16* uT = (_Float16*)(ubuf + NE);
  __hip_bfloat16* wiohi = (__hip_bfloat16*)(uT + NE);
  __hip_bfloat16* wiolo = wiohi + 786432;
  __hip_bfloat16* wohi  = wiolo + 786432;
  __hip_bfloat16* wolo  = wohi + 262144;
  __hip_bfloat16* ohhi = (__hip_bfloat16*)ubuf;  // alias: ubuf dead after transp
  __hip_bfloat16* ohlo = ohhi + NE;

  wconv_kernel<<<dim3(1024), 256, 0, stream>>>(wio, wo, wiohi, wiolo, wohi, wolo);
  proj_qkv_kernel<<<dim3(64, 4, 3), 256, 0, stream>>>(q_in, k_in, v_in, wiohi,
                                                      bio, pw, sw, qbuf, kbuf,
                                                      (_Float16*)ubuf);
  transp_kernel<<<dim3(32, 8, 4), 256, 0, stream>>>((const _Float16*)ubuf, uT);
  attn_kernel<<<dim3(512), 256, 0, stream>>>(qbuf, kbuf, uT, pw, sw,
                                             ohhi, ohlo);
  out_proj_kernel<<<dim3(64, 8), 256, 0, stream>>>(ohhi, ohlo, wohi, wolo,
                                                   bo, (float*)d_out);
}

// Round 14
// 268.585 us; speedup vs baseline: 1.5671x; 1.0104x over previous
//
#include <hip/hip_runtime.h>
#include <hip/hip_bf16.h>

// Problem constants (L,N,E,H,D) = (2048,4,512,8,64)
#define E_DIM 512
#define N_BATCH 4
#define L_SEQ 2048
#define N_HEADS 8
#define H_DIM 64
#define N_ROWS (L_SEQ * N_BATCH) /* 8192 */
#define EPS_F 1e-6f
#define SC_Q 0.18033688f  /* 0.125 * log2(e): scores come out in log2 space */

typedef __attribute__((ext_vector_type(8))) short bf16x8;
typedef __attribute__((ext_vector_type(8))) _Float16 f16x8;
typedef __attribute__((ext_vector_type(4))) float f32x4;
typedef __attribute__((ext_vector_type(16))) float f32x16;

__device__ __forceinline__ void split2(float f, __hip_bfloat16& h, __hip_bfloat16& l) {
  h = __float2bfloat16(f);
  l = __float2bfloat16(f - __bfloat162float(h));
}

__device__ __forceinline__ unsigned int packf16(float a, float b) {
  union { _Float16 h[2]; unsigned int u; } c;
  c.h[0] = (_Float16)a;  // RN casts: unbiased (RTZ pkrtz would bias softmax weights)
  c.h[1] = (_Float16)b;
  return c.u;
}

// ---------------------------------------------------------------------------
// Kernel W: pre-split weights fp32 -> bf16 hi/lo.  (wiolo now unused by proj
// but kept for layout stability; wohi/wolo feed out_proj.)
// ---------------------------------------------------------------------------
__global__ __launch_bounds__(256) void wconv_kernel(
    const float* __restrict__ wio, const float* __restrict__ wo,
    __hip_bfloat16* __restrict__ wiohi, __hip_bfloat16* __restrict__ wiolo,
    __hip_bfloat16* __restrict__ wohi, __hip_bfloat16* __restrict__ wolo) {
  const int g = blockIdx.x * 256 + threadIdx.x;
  const float* src;
  __hip_bfloat16 *dh, *dl;
  int i;
  if (g < 196608) { src = wio; dh = wiohi; dl = wiolo; i = g * 4; }
  else            { src = wo;  dh = wohi;  dl = wolo;  i = (g - 196608) * 4; }
  const float4 f = *(const float4*)(src + i);
  alignas(8) __hip_bfloat16 h[4], l[4];
  split2(f.x, h[0], l[0]); split2(f.y, h[1], l[1]);
  split2(f.z, h[2], l[2]); split2(f.w, h[3], l[3]);
  *(uint2*)(dh + i) = *(const uint2*)h;
  *(uint2*)(dl + i) = *(const uint2*)l;
}

// ---------------------------------------------------------------------------
// Kernel A: packed QKV projection via MFMA, hi/lo 2-pass (hh + lh).  Q folds
// the softmax scale, stores fp16; K fp16; V stores u = max(v+sh,eps)^p fp16.
//
// v14 (proj TLP): proj is latency-stalled (v12 counters: MfmaUtil 5.7%,
// VALUBusy 14.9%, Occ 15.6% -- all pipes idle; FLOP floor ~13us, BW floor
// ~9us).  Its grid was the cap: (64,4,3)=768 blocks = 3 blocks/CU.  Halve
// the row-tile 128->64: grid (128,4,3)=1536 = 6 blocks/CU; LDS 30.7->20.5KB;
// acc halves to 8 x f32x4 (~48 live regs -- NO spill risk, unlike attn's
// v7-v9 whose ~130-reg live set hit the allocator wall).  Per-wave structure
// is the proven one with the rt dim removed (ar0 = wv*16+lidx; R = row0 +
// wv*16 + quad*4 + reg).  Single 32-k window x16 (v1-v11 proven); v13's
// double-window was neutral and is dropped to keep one variable.
// ---------------------------------------------------------------------------
__global__ __launch_bounds__(256, 3) void proj_qkv_kernel(
    const float* __restrict__ xq, const float* __restrict__ xk,
    const float* __restrict__ xv, const __hip_bfloat16* __restrict__ whi,
    const float* __restrict__ bias, const float* __restrict__ pw,
    const float* __restrict__ sw,
    _Float16* __restrict__ qbuf, _Float16* __restrict__ kbuf,
    _Float16* __restrict__ ubuf) {
  __shared__ __hip_bfloat16 Xh[64][40];
  __shared__ __hip_bfloat16 Xl[64][40];
  __shared__ __hip_bfloat16 Wh[128][40];
  const int z = blockIdx.z;
  const int row0 = blockIdx.x * 64;
  const int col0 = blockIdx.y * 128;
  const float* __restrict__ xsrc = (z == 0) ? xq : (z == 1) ? xk : xv;
  const int tid = threadIdx.x;
  const int lane = tid & 63;
  const int wv = tid >> 6;
  const int lidx = lane & 15;
  const int quad = lane >> 4;
  const int xrow = tid >> 2;        // X staging row 0..63
  const int xcol = (tid & 3) * 8;   // X staging col base (8 floats/thread)
  const int wrow = tid >> 1;        // W staging row 0..127
  const int wcol = (tid & 1) * 16;

  f32x4 acc[8];
#pragma unroll
  for (int ct = 0; ct < 8; ++ct) acc[ct] = (f32x4){0.f, 0.f, 0.f, 0.f};

  const int ar0 = wv * 16 + lidx;   // this wave's 16 output rows

  for (int kt = 0; kt < 16; ++kt) {
    const int k0 = kt * 32;
    {
      const float* xp = xsrc + (size_t)(row0 + xrow) * E_DIM + k0 + xcol;
      float f[8];
      *(float4*)&f[0] = ((const float4*)xp)[0];
      *(float4*)&f[4] = ((const float4*)xp)[1];
      alignas(16) __hip_bfloat16 hi[8], lo[8];
#pragma unroll
      for (int jj = 0; jj < 8; ++jj) split2(f[jj], hi[jj], lo[jj]);
      *(uint4*)&Xh[xrow][xcol] = *(const uint4*)hi;
      *(uint4*)&Xl[xrow][xcol] = *(const uint4*)lo;
    }
    {
      const size_t wof = (size_t)(z * E_DIM + col0 + wrow) * E_DIM + k0 + wcol;
      *(uint4*)&Wh[wrow][wcol]     = ((const uint4*)(whi + wof))[0];
      *(uint4*)&Wh[wrow][wcol + 8] = ((const uint4*)(whi + wof))[1];
    }
    __syncthreads();

    const bf16x8 ah = *(const bf16x8*)&Xh[ar0][quad * 8];
    const bf16x8 al = *(const bf16x8*)&Xl[ar0][quad * 8];
#pragma unroll
    for (int ct = 0; ct < 8; ++ct) {
      const bf16x8 bh = *(const bf16x8*)&Wh[ct * 16 + lidx][quad * 8];
      acc[ct] = __builtin_amdgcn_mfma_f32_16x16x32_bf16(ah, bh, acc[ct], 0, 0, 0);
      acc[ct] = __builtin_amdgcn_mfma_f32_16x16x32_bf16(al, bh, acc[ct], 0, 0, 0);
    }
    __syncthreads();
  }

  if (z < 2) {
    _Float16* __restrict__ dst = (z == 0) ? qbuf : kbuf;
    const float scale = (z == 0) ? SC_Q : 1.0f;
    float bv[8];
#pragma unroll
    for (int ct = 0; ct < 8; ++ct) bv[ct] = bias[z * E_DIM + col0 + ct * 16 + lidx];
#pragma unroll
    for (int ct = 0; ct < 8; ++ct) {
      const int e = col0 + ct * 16 + lidx;
      const int h = e >> 6, d = e & 63;
#pragma unroll
      for (int reg = 0; reg < 4; ++reg) {
        const int R = row0 + wv * 16 + quad * 4 + reg;
        const int lpos = R >> 2, nb = R & 3;
        dst[(((size_t)nb * N_HEADS + h) * L_SEQ + lpos) * H_DIM + d] =
            (_Float16)((acc[ct][reg] + bv[ct]) * scale);
      }
    }
  } else {
    float bv[8], pv[8], sv[8];
#pragma unroll
    for (int ct = 0; ct < 8; ++ct) {
      const int e = col0 + ct * 16 + lidx;
      bv[ct] = bias[2 * E_DIM + e]; pv[ct] = pw[e]; sv[ct] = sw[e];
    }
#pragma unroll
    for (int ct = 0; ct < 8; ++ct) {
      const int e = col0 + ct * 16 + lidx;
      const int h = e >> 6, d = e & 63;
#pragma unroll
      for (int reg = 0; reg < 4; ++reg) {
        const int R = row0 + wv * 16 + quad * 4 + reg;
        const int lpos = R >> 2, nb = R & 3;
        const float y = acc[ct][reg] + bv[ct];
        const float vp = fmaxf(y + sv[ct], EPS_F);
        ubuf[(((size_t)nb * N_HEADS + h) * L_SEQ + lpos) * H_DIM + d] =
            (_Float16)__powf(vp, pv[ct]);
      }
    }
  }
}

// ---------------------------------------------------------------------------
// Kernel T: transpose u (n,h,l,d) fp16 -> u^T (n,h,d,l) fp16.
// ---------------------------------------------------------------------------
__global__ __launch_bounds__(256) void transp_kernel(
    const _Float16* __restrict__ u, _Float16* __restrict__ uT) {
  __shared__ _Float16 T[64][72];
  const int lt = blockIdx.x, h = blockIdx.y, nb = blockIdx.z;
  const int tid = threadIdx.x;
  const int r = tid >> 2;
  const int cb = (tid & 3) * 16;
  const size_t srcbase = ((size_t)nb * N_HEADS + h) * L_SEQ + lt * 64;
  {
    const _Float16* p = u + (srcbase + r) * H_DIM + cb;
    *(uint4*)&T[r][cb + 0] = ((const uint4*)p)[0];
    *(uint4*)&T[r][cb + 8] = ((const uint4*)p)[1];
  }
  __syncthreads();
  alignas(16) _Float16 hv[16];
#pragma unroll
  for (int j = 0; j < 16; ++j) hv[j] = T[cb + j][r];
  const size_t dst = (((size_t)nb * N_HEADS + h) * H_DIM + r) * L_SEQ + lt * 64 + cb;
  *(uint4*)(uT + dst)     = ((const uint4*)hv)[0];
  *(uint4*)(uT + dst + 8) = ((const uint4*)hv)[1];
}

// ---------------------------------------------------------------------------
// Kernel B: fp16 MFMA flash attention (v11 champion, verbatim).  S^T
// orientation (A=K, B=Q); P in B-operand layout via permlane32_swap (T12);
// setprio around MFMA clusters (T5); XCD-clustered decode (T1); 256-row
// double window, two-barrier ordering; cross-s-group LDS reduction.
// Grid 512 x 256 thr.
// ---------------------------------------------------------------------------
__global__ __launch_bounds__(256, 2) void attn_kernel(
    const _Float16* __restrict__ qbuf, const _Float16* __restrict__ kbuf,
    const _Float16* __restrict__ uT, const float* __restrict__ pw,
    const float* __restrict__ sw, __hip_bfloat16* __restrict__ ohhi,
    __hip_bfloat16* __restrict__ ohlo) {
  __shared__ union {
    struct { _Float16 Ks0[128][72]; _Float16 Us0[64][136];
             _Float16 Ks1[128][72]; _Float16 Us1[64][136]; } st;
    struct { float A[2][64][64]; float lA[2][2][64]; } red;
  } sm;
  // XCD-clustered decode: f -> xcd = f&7 (dispatch round-robin); XCD x owns
  // heads [4x,4x+4) x all 16 q-tiles.  Bijective: f = ((hidx&3)*16+qt)*8+xcd.
  const int f = blockIdx.x;              // 0..511
  const int xcd = f & 7;
  const int j = f >> 3;                  // 0..63
  const int qt = j & 15;
  const int hidx = xcd * 4 + (j >> 4);   // 0..31
  const int h = hidx & 7, nb = hidx >> 3;
  const int q0 = qt * 128;
  const int tid = threadIdx.x;
  const int lane = tid & 63;
  const int w = tid >> 6;           // wave 0..3
  const int wv = w & 1;             // q-half of the block tile
  const int sg = w >> 1;            // s-group 0..1
  const int lm = lane & 31;
  const int kg = lane >> 5;         // k-group within MFMA operands
  const int srow = tid >> 1;        // K staging row 0..127
  const int scb = (tid & 1) * 32;   // K staging col base (fp16 units)
  const int urow = tid >> 2;        // U staging row (d) 0..63
  const int ucb = (tid & 3) * 32;   // U staging col base (s units)
  const size_t headbase = ((size_t)nb * N_HEADS + h) * L_SEQ;
  const size_t dbase = ((size_t)nb * N_HEADS + h) * H_DIM;

  // hoist Q B-frags straight from global (no Q LDS): q(nt) = q0+wv*64+nt*32+lm
  f16x8 bq[2][4];
#pragma unroll
  for (int nt = 0; nt < 2; ++nt)
#pragma unroll
    for (int kc = 0; kc < 4; ++kc)
      bq[nt][kc] = *(const f16x8*)(qbuf +
          (headbase + q0 + wv * 64 + nt * 32 + lm) * H_DIM + kc * 16 + kg * 8);

  f32x16 o[2][2];  // [q-half nt][d-half mt2]
  o[0][0] = (f32x16)(0.f); o[0][1] = (f32x16)(0.f);
  o[1][0] = (f32x16)(0.f); o[1][1] = (f32x16)(0.f);
  float lsum[2] = {0.f, 0.f};

  // compute one 64-row s-slice from a staged half-tile
  auto do_half = [&](const _Float16 (&Ks)[128][72], const _Float16 (&Us)[64][136]) {
    const int sr = sg * 64;  // this wave's s-rows within the staged 128

    // ---- S^T: sc[nt][mt], C-layout row = s_local, col = q (lane&31) ----
    f32x16 sc[2][2];
    sc[0][0] = (f32x16)(0.f); sc[0][1] = (f32x16)(0.f);
    sc[1][0] = (f32x16)(0.f); sc[1][1] = (f32x16)(0.f);
    __builtin_amdgcn_s_setprio(1);
#pragma unroll
    for (int kc = 0; kc < 4; ++kc) {
      const f16x8 ak0 = *(const f16x8*)&Ks[sr + lm][kc * 16 + kg * 8];
      const f16x8 ak1 = *(const f16x8*)&Ks[sr + 32 + lm][kc * 16 + kg * 8];
      sc[0][0] = __builtin_amdgcn_mfma_f32_32x32x16_f16(ak0, bq[0][kc], sc[0][0], 0, 0, 0);
      sc[0][1] = __builtin_amdgcn_mfma_f32_32x32x16_f16(ak1, bq[0][kc], sc[0][1], 0, 0, 0);
      sc[1][0] = __builtin_amdgcn_mfma_f32_32x32x16_f16(ak0, bq[1][kc], sc[1][0], 0, 0, 0);
      sc[1][1] = __builtin_amdgcn_mfma_f32_32x32x16_f16(ak1, bq[1][kc], sc[1][1], 0, 0, 0);
    }
    __builtin_amdgcn_s_setprio(0);

    // ---- p = exp2(score); pack fp16 pairs; per-lane l partial sum ----
    unsigned int P2[2][2][4][2];
#pragma unroll
    for (int nt = 0; nt < 2; ++nt)
#pragma unroll
      for (int mt = 0; mt < 2; ++mt)
#pragma unroll
        for (int g = 0; g < 4; ++g) {
          const float p0 = __builtin_amdgcn_exp2f(sc[nt][mt][4 * g + 0]);
          const float p1 = __builtin_amdgcn_exp2f(sc[nt][mt][4 * g + 1]);
          const float p2 = __builtin_amdgcn_exp2f(sc[nt][mt][4 * g + 2]);
          const float p3 = __builtin_amdgcn_exp2f(sc[nt][mt][4 * g + 3]);
          lsum[nt] += (p0 + p1) + (p2 + p3);
          P2[nt][mt][g][0] = packf16(p0, p1);
          P2[nt][mt][g][1] = packf16(p2, p3);
        }

    // ---- PV: O^T += U^T @ P^T; P B-frags via permlane32_swap (T12).
    //      v_permlane32_swap_b32 a,b: a[32..63] <-> b[0..31].  With
    //      a=x0,b=y0: a' = (l<32 ? x0[l] : y0[l-32]) == old bp.u[0];
    //      b' = (l<32 ? x0[l+32] : y0[l]) == old bp.u[2].  Bit-identical
    //      to the shfl_xor+cndmask network it replaces. ----
    __builtin_amdgcn_s_setprio(1);
#pragma unroll
    for (int kc = 0; kc < 4; ++kc) {
      const int mt = kc >> 1;
      const f16x8 au0 = *(const f16x8*)&Us[lm][sr + kc * 16 + kg * 8];
      const f16x8 au1 = *(const f16x8*)&Us[32 + lm][sr + kc * 16 + kg * 8];
#pragma unroll
      for (int nt = 0; nt < 2; ++nt) {
        const int gx = (2 * kc) & 3, gy = (2 * kc + 1) & 3;
        unsigned int a0 = P2[nt][mt][gx][0], b0 = P2[nt][mt][gy][0];
        unsigned int a1 = P2[nt][mt][gx][1], b1 = P2[nt][mt][gy][1];
        asm("v_permlane32_swap_b32 %0, %1" : "+v"(a0), "+v"(b0));
        asm("v_permlane32_swap_b32 %0, %1" : "+v"(a1), "+v"(b1));
        union { unsigned int u[4]; f16x8 v; } bp;
        bp.u[0] = a0;  // j0..3: s = kc*16+kg*8+0..3
        bp.u[1] = a1;
        bp.u[2] = b0;  // j4..7: s = kc*16+kg*8+4..7
        bp.u[3] = b1;
        o[nt][0] = __builtin_amdgcn_mfma_f32_32x32x16_f16(au0, bp.v, o[nt][0], 0, 0, 0);
        o[nt][1] = __builtin_amdgcn_mfma_f32_32x32x16_f16(au1, bp.v, o[nt][1], 0, 0, 0);
      }
    }
    __builtin_amdgcn_s_setprio(0);
  };

  for (int it = 0; it < 8; ++it) {
    const int s0 = it * 256;
    __syncthreads();  // B1: prior window's frag reads complete
    {
      const _Float16* kp = kbuf + (headbase + s0 + srow) * H_DIM + scb;
      *(uint4*)&sm.st.Ks0[srow][scb + 0]  = ((const uint4*)kp)[0];
      *(uint4*)&sm.st.Ks0[srow][scb + 8]  = ((const uint4*)kp)[1];
      *(uint4*)&sm.st.Ks0[srow][scb + 16] = ((const uint4*)kp)[2];
      *(uint4*)&sm.st.Ks0[srow][scb + 24] = ((const uint4*)kp)[3];
      const _Float16* kq = kbuf + (headbase + s0 + 128 + srow) * H_DIM + scb;
      *(uint4*)&sm.st.Ks1[srow][scb + 0]  = ((const uint4*)kq)[0];
      *(uint4*)&sm.st.Ks1[srow][scb + 8]  = ((const uint4*)kq)[1];
      *(uint4*)&sm.st.Ks1[srow][scb + 16] = ((const uint4*)kq)[2];
      *(uint4*)&sm.st.Ks1[srow][scb + 24] = ((const uint4*)kq)[3];
      const _Float16* up = uT + (dbase + urow) * L_SEQ + s0 + ucb;
      *(uint4*)&sm.st.Us0[urow][ucb + 0]  = ((const uint4*)up)[0];
      *(uint4*)&sm.st.Us0[urow][ucb + 8]  = ((const uint4*)up)[1];
      *(uint4*)&sm.st.Us0[urow][ucb + 16] = ((const uint4*)up)[2];
      *(uint4*)&sm.st.Us0[urow][ucb + 24] = ((const uint4*)up)[3];
      const _Float16* uq = up + 128;
      *(uint4*)&sm.st.Us1[urow][ucb + 0]  = ((const uint4*)uq)[0];
      *(uint4*)&sm.st.Us1[urow][ucb + 8]  = ((const uint4*)uq)[1];
      *(uint4*)&sm.st.Us1[urow][ucb + 16] = ((const uint4*)uq)[2];
      *(uint4*)&sm.st.Us1[urow][ucb + 24] = ((const uint4*)uq)[3];
    }
    __syncthreads();  // B2: staged 256-row tile visible to all waves

    do_half(sm.st.Ks0, sm.st.Us0);
    do_half(sm.st.Ks1, sm.st.Us1);
  }

  // ---- cross-s-group reduction in LDS: sg1 publishes (o, lsum), sg0
  //      accumulates.  XOR-swizzled float4 slots keep accesses at the
  //      8-dwords/bank wave64 minimum (conflict-free).  ----
  float* redA = &sm.red.A[0][0][0];
  float* lrA = &sm.red.lA[0][0][0];

  __syncthreads();  // loop's trailing frag reads complete before LDS reuse
  if (sg == 1) {
#pragma unroll
    for (int nt = 0; nt < 2; ++nt) {
      lrA[(wv * 2 + nt) * 64 + lane] = lsum[nt];
#pragma unroll
      for (int mt2 = 0; mt2 < 2; ++mt2)
#pragma unroll
        for (int g = 0; g < 4; ++g) {
          const int i4 = ((nt * 2 + mt2) * 4 + g) ^ (lane & 7);
          float4 v = {o[nt][mt2][4 * g + 0], o[nt][mt2][4 * g + 1],
                      o[nt][mt2][4 * g + 2], o[nt][mt2][4 * g + 3]};
          *(float4*)(redA + ((size_t)(wv * 64 + lane)) * 64 + i4 * 4) = v;
        }
    }
  }
  __syncthreads();
  if (sg == 1) return;  // sg0 past this point; no further barriers
#pragma unroll
  for (int nt = 0; nt < 2; ++nt) {
    lsum[nt] += lrA[(wv * 2 + nt) * 64 + lane];
#pragma unroll
    for (int mt2 = 0; mt2 < 2; ++mt2)
#pragma unroll
      for (int g = 0; g < 4; ++g) {
        const int i4 = ((nt * 2 + mt2) * 4 + g) ^ (lane & 7);
        const float4 v =
            *(const float4*)(redA + ((size_t)(wv * 64 + lane)) * 64 + i4 * 4);
        o[nt][mt2][4 * g + 0] += v.x; o[nt][mt2][4 * g + 1] += v.y;
        o[nt][mt2][4 * g + 2] += v.z; o[nt][mt2][4 * g + 3] += v.w;
      }
  }

  // ---- epilogue: finish l across kg halves, GeM inverse, packed stores ----
#pragma unroll
  for (int nt = 0; nt < 2; ++nt) {
    const float l = lsum[nt] + __shfl_xor(lsum[nt], 32);
    const float inv = 1.0f / l;
    const int qg = q0 + wv * 64 + nt * 32 + lm;
    const size_t base = ((size_t)qg * N_BATCH + nb) * E_DIM + h * H_DIM;
#pragma unroll
    for (int mt2 = 0; mt2 < 2; ++mt2)
#pragma unroll
      for (int g = 0; g < 4; ++g) {
        alignas(8) __hip_bfloat16 hb[4], lb[4];
#pragma unroll
        for (int i = 0; i < 4; ++i) {
          const int d = mt2 * 32 + 8 * g + 4 * kg + i;
          const int e = h * H_DIM + d;
          const float pooled = o[nt][mt2][4 * g + i] * inv;
          const float val = __powf(fmaxf(pooled, EPS_F), 1.0f / pw[e]) - sw[e];
          split2(val, hb[i], lb[i]);
        }
        const int d0 = mt2 * 32 + 8 * g + 4 * kg;
        *(uint2*)(ohhi + base + d0) = *(const uint2*)hb;
        *(uint2*)(ohlo + base + d0) = *(const uint2*)lb;
      }
  }
}

// ---------------------------------------------------------------------------
// Kernel C: output projection via MFMA, hi/lo 3-pass.  (unchanged)
// ---------------------------------------------------------------------------
__global__ __launch_bounds__(256, 4) void out_proj_kernel(
    const __hip_bfloat16* __restrict__ xhi, const __hip_bfloat16* __restrict__ xlo,
    const __hip_bfloat16* __restrict__ whi, const __hip_bfloat16* __restrict__ wlo,
    const float* __restrict__ bias, float* __restrict__ out) {
  __shared__ __hip_bfloat16 Xh[128][40];
  __shared__ __hip_bfloat16 Xl[128][40];
  __shared__ __hip_bfloat16 Wh[64][40];
  __shared__ __hip_bfloat16 Wl[64][40];
  const int row0 = blockIdx.x * 128;
  const int col0 = blockIdx.y * 64;
  const int tid = threadIdx.x;
  const int lane = tid & 63;
  const int wv = tid >> 6;
  const int lidx = lane & 15;
  const int quad = lane >> 4;
  const int srow = tid >> 1;
  const int scol = (tid & 1) * 16;
  const int wrow = tid >> 2;
  const int wcol = (tid & 3) * 8;

  f32x4 acc[2][4];
#pragma unroll
  for (int rt = 0; rt < 2; ++rt)
#pragma unroll
    for (int ct = 0; ct < 4; ++ct) acc[rt][ct] = (f32x4){0.f, 0.f, 0.f, 0.f};

  const int ar0 = wv * 32 + lidx;

  for (int kt = 0; kt < 16; ++kt) {
    const int k0 = kt * 32;
    {
      const size_t xof = (size_t)(row0 + srow) * E_DIM + k0 + scol;
      *(uint4*)&Xh[srow][scol]     = ((const uint4*)(xhi + xof))[0];
      *(uint4*)&Xh[srow][scol + 8] = ((const uint4*)(xhi + xof))[1];
      *(uint4*)&Xl[srow][scol]     = ((const uint4*)(xlo + xof))[0];
      *(uint4*)&Xl[srow][scol + 8] = ((const uint4*)(xlo + xof))[1];
      const size_t wof = (size_t)(col0 + wrow) * E_DIM + k0 + wcol;
      *(uint4*)&Wh[wrow][wcol] = *(const uint4*)(whi + wof);
      *(uint4*)&Wl[wrow][wcol] = *(const uint4*)(wlo + wof);
    }
    __syncthreads();

    const bf16x8 ah0 = *(const bf16x8*)&Xh[ar0][quad * 8];
    const bf16x8 ah1 = *(const bf16x8*)&Xh[ar0 + 16][quad * 8];
    const bf16x8 al0 = *(const bf16x8*)&Xl[ar0][quad * 8];
    const bf16x8 al1 = *(const bf16x8*)&Xl[ar0 + 16][quad * 8];
#pragma unroll
    for (int ct = 0; ct < 4; ++ct) {
      const bf16x8 bh = *(const bf16x8*)&Wh[ct * 16 + lidx][quad * 8];
      const bf16x8 bl = *(const bf16x8*)&Wl[ct * 16 + lidx][quad * 8];
      acc[0][ct] = __builtin_amdgcn_mfma_f32_16x16x32_bf16(ah0, bh, acc[0][ct], 0, 0, 0);
      acc[0][ct] = __builtin_amdgcn_mfma_f32_16x16x32_bf16(al0, bh, acc[0][ct], 0, 0, 0);
      acc[0][ct] = __builtin_amdgcn_mfma_f32_16x16x32_bf16(ah0, bl, acc[0][ct], 0, 0, 0);
      acc[1][ct] = __builtin_amdgcn_mfma_f32_16x16x32_bf16(ah1, bh, acc[1][ct], 0, 0, 0);
      acc[1][ct] = __builtin_amdgcn_mfma_f32_16x16x32_bf16(al1, bh, acc[1][ct], 0, 0, 0);
      acc[1][ct] = __builtin_amdgcn_mfma_f32_16x16x32_bf16(ah1, bl, acc[1][ct], 0, 0, 0);
    }
    __syncthreads();
  }

  float bv[4];
#pragma unroll
  for (int ct = 0; ct < 4; ++ct) bv[ct] = bias[col0 + ct * 16 + lidx];
#pragma unroll
  for (int rt = 0; rt < 2; ++rt)
#pragma unroll
    for (int ct = 0; ct < 4; ++ct) {
      const int c = col0 + ct * 16 + lidx;
#pragma unroll
      for (int reg = 0; reg < 4; ++reg) {
        const int R = row0 + wv * 32 + rt * 16 + quad * 4 + reg;
        out[(size_t)R * E_DIM + c] = acc[rt][ct][reg] + bv[ct];
      }
    }
}

extern "C" void kernel_launch(void* const* d_in, const int* in_sizes, int n_in,
                              void* d_out, int out_size, void* d_ws, size_t ws_size,
                              hipStream_t stream) {
  const float* q_in = (const float*)d_in[0];
  const float* k_in = (const float*)d_in[1];
  const float* v_in = (const float*)d_in[2];
  const float* wio  = (const float*)d_in[3];
  const float* bio  = (const float*)d_in[4];
  const float* wo   = (const float*)d_in[5];
  const float* bo   = (const float*)d_in[6];
  const float* pw   = (const float*)d_in[7];
  const float* sw   = (const float*)d_in[8];

  // Workspace layout unchanged (ubuf region holds fp16 u in its first half;
  // ohhi/ohlo alias it after transp consumes u).
  const size_t NE = (size_t)N_ROWS * E_DIM;
  _Float16* qbuf = (_Float16*)d_ws;
  _Float16* kbuf = qbuf + NE;
  float* ubuf = (float*)(kbuf + NE);
  _Float16* uT = (_Float16*)(ubuf + NE);
  __hip_bfloat16* wiohi = (__hip_bfloat16*)(uT + NE);
  __hip_bfloat16* wiolo = wiohi + 786432;
  __hip_bfloat16* wohi  = wiolo + 786432;
  __hip_bfloat16* wolo  = wohi + 262144;
  __hip_bfloat16* ohhi = (__hip_bfloat16*)ubuf;  // alias: ubuf dead after transp
  __hip_bfloat16* ohlo = ohhi + NE;

  wconv_kernel<<<dim3(1024), 256, 0, stream>>>(wio, wo, wiohi, wiolo, wohi, wolo);
  proj_qkv_kernel<<<dim3(128, 4, 3), 256, 0, stream>>>(q_in, k_in, v_in, wiohi,
                                                       bio, pw, sw, qbuf, kbuf,
                                                       (_Float16*)ubuf);
  transp_kernel<<<dim3(32, 8, 4), 256, 0, stream>>>((const _Float16*)ubuf, uT);
  attn_kernel<<<dim3(512), 256, 0, stream>>>(qbuf, kbuf, uT, pw, sw,
                                             ohhi, ohlo);
  out_proj_kernel<<<dim3(64, 8), 256, 0, stream>>>(ohhi, ohlo, wohi, wolo,
                                                   bo, (float*)d_out);
}